// Round 15
// baseline (67.130 us; speedup 1.0000x reference)
//
#include <hip/hip_runtime.h>

#define NB 16           // B images
#define NP 16000        // proposals per image
#define NG 256          // gt boxes per image
#define NM (NP + NG)    // proposals + gt = 16256
#define NSTRIP 254      // NM / 64
#define NS 512          // samples per image
#define NCLS 91
#define SL1_BETA (1.0f/9.0f)
#define MATCHX 32       // match blocks per image (512 proposals each)
#define STATSX 4        // stats blocks per image

// ---------------------------------------------------------------------------
// K1 = match + softmax-stats rider.
// match (bx < 32): TWO proposals per thread (jA, jB = jA+256) — each GT's
//   single ds_read_b128 (one broadcast address, conflict-free) feeds 128
//   pairs. GT area computed in VALU (no gar LDS read): LDS instrs/iter 2 -> 1.
//   Inner loop = exact predicate only (R5-proven):
//     iou >= 0.5  <=>  3*inter >= ap+ga  via  fmaf(inter,3,-tt) >= 0.
//   Qualifier masks qmA[8]/qmB[8] in REGISTERS: outer loop unrolled (8,
//   compile-time index), inner runtime-32 with #pragma unroll 4 (~8KB body,
//   I$-safe; no R7 spill). qcnt==1 -> argmax free; qcnt>1 (rare) -> exact
//   cross-product argmax over set bits (ascending g + strict improve =
//   first-max tie rule). GT self-rows flow through the generic path.
//   Output: (gstar<<16)|label, 0 = negative.
// stats (bx >= 32): per-row logsumexp (proven rider; hides under match).
// grid = (36, NB) x 256. No atomics, no fences.
// ---------------------------------------------------------------------------
__global__ __launch_bounds__(256) void k1_kernel(
    const float4* __restrict__ props4,      // [NB*NP]
    const float4* __restrict__ gt4,         // [NB*NG]
    const int*    __restrict__ gt_labels,   // [NB*NG]
    const float*  __restrict__ logits,      // [NB*NS, NCLS]
    unsigned int* __restrict__ posinfo,     // [NB*NM]
    float*        __restrict__ stats)       // [NB*NS]
{
    const int b    = blockIdx.y;
    const int bx   = blockIdx.x;
    const int tid  = threadIdx.x;
    const int lane = tid & 63;
    const int wid  = tid >> 6;

    if (bx >= MATCHX) {
        // ---- softmax stats: 64 blocks x 4 waves; 32 rows per wave ----
        const int sid = (bx - MATCHX) * NB + b;          // 0..63
        for (int rr = 0; rr < 32; ++rr) {
            const int r = sid * 128 + wid * 32 + rr;
            const float* row = logits + (size_t)r * NCLS;
            float a = (lane < NCLS)      ? row[lane]      : -3.0e38f;
            float c = (lane + 64 < NCLS) ? row[lane + 64] : -3.0e38f;
            float mx = fmaxf(a, c);
            #pragma unroll
            for (int o = 32; o; o >>= 1) mx = fmaxf(mx, __shfl_xor(mx, o, 64));
            float ss = 0.0f;
            if (lane < NCLS)      ss += expf(a - mx);
            if (lane + 64 < NCLS) ss += expf(c - mx);
            #pragma unroll
            for (int o = 32; o; o >>= 1) ss += __shfl_xor(ss, o, 64);
            if (lane == 0) stats[r] = mx + logf(ss);
        }
        return;
    }

    // ---- match ----
    __shared__ float4 gbox[NG];     // 4 KB (boxes only; area in VALU)

    gbox[tid] = gt4[(size_t)b * NG + tid];
    __syncthreads();

    const int jA = bx * 512 + tid;             // < NM always
    const int jB = jA + 256;                   // invalid only in last block
    const bool vB = (jB < NM);                 // wave-uniform (128|64 split)

    const float4 pA = (jA < NP) ? props4[(size_t)b * NP + jA] : gbox[jA - NP];
    float4 pB = make_float4(0.f, 0.f, 0.f, 0.f);   // dummy never qualifies
    if (vB) pB = (jB < NP) ? props4[(size_t)b * NP + jB] : gbox[jB - NP];
    const float apA = (pA.z - pA.x) * (pA.w - pA.y);
    const float apB = (pB.z - pB.x) * (pB.w - pB.y);

    unsigned qmA[8], qmB[8];
    int qcA = 0, qcB = 0, gfA = 0, gfB = 0;
    #pragma unroll
    for (int w = 0; w < 8; ++w) {              // outer unrolled: qm regs static
        unsigned mA = 0, mB = 0;
        #pragma unroll 4
        for (int t = 0; t < 32; ++t) {         // runtime inner: I$-safe
            const float4 gb = gbox[w * 32 + t];            // 1 ds_read_b128
            const float  ga = (gb.z - gb.x) * (gb.w - gb.y); // VALU (shared A/B)
            {   // proposal A
                float lx = fmaxf(gb.x, pA.x), ly = fmaxf(gb.y, pA.y);
                float rx = fminf(gb.z, pA.z), ry = fminf(gb.w, pA.w);
                float ww = fmaxf(rx - lx, 0.0f), hh = fmaxf(ry - ly, 0.0f);
                float inter = ww * hh;
                float tt = ga + apA;
                if (fmaf(inter, 3.0f, -tt) >= 0.0f) mA |= (1u << t);
            }
            {   // proposal B
                float lx = fmaxf(gb.x, pB.x), ly = fmaxf(gb.y, pB.y);
                float rx = fminf(gb.z, pB.z), ry = fminf(gb.w, pB.w);
                float ww = fmaxf(rx - lx, 0.0f), hh = fmaxf(ry - ly, 0.0f);
                float inter = ww * hh;
                float tt = ga + apB;
                if (fmaf(inter, 3.0f, -tt) >= 0.0f) mB |= (1u << t);
            }
        }
        qmA[w] = mA; qmB[w] = mB;
        if (qcA == 0 && mA) gfA = w * 32 + (__ffs(mA) - 1);
        if (qcB == 0 && mB) gfB = w * 32 + (__ffs(mB) - 1);
        qcA += __popc(mA);
        qcB += __popc(mB);
    }

    if (qcA > 0) {
        int gstar = gfA;
        if (qcA > 1) {                         // rare: exact argmax over set bits
            float ib = -1.0f, ub = 1.0f; gstar = 0;
            #pragma unroll
            for (int w = 0; w < 8; ++w) {
                unsigned m = qmA[w];
                while (m) {
                    int t = __ffs(m) - 1; m &= m - 1;
                    int g = w * 32 + t;
                    const float4 gb = gbox[g];
                    float lx = fmaxf(gb.x, pA.x), ly = fmaxf(gb.y, pA.y);
                    float rx = fminf(gb.z, pA.z), ry = fminf(gb.w, pA.w);
                    float ww = fmaxf(rx - lx, 0.0f), hh = fmaxf(ry - ly, 0.0f);
                    float inter = ww * hh;
                    float ga = (gb.z - gb.x) * (gb.w - gb.y);
                    float u  = (ga + apA) - inter;
                    // inter/u > ib/ub <=> inter*ub > ib*u ; ascending g +
                    // strict improve == first-max tie rule
                    if (inter * ub > ib * u) { ib = inter; ub = u; gstar = g; }
                }
            }
        }
        posinfo[(size_t)b * NM + jA] =
            ((unsigned)gstar << 16) | (unsigned)gt_labels[b * NG + gstar];
    } else {
        posinfo[(size_t)b * NM + jA] = 0;
    }

    if (vB) {
        if (qcB > 0) {
            int gstar = gfB;
            if (qcB > 1) {
                float ib = -1.0f, ub = 1.0f; gstar = 0;
                #pragma unroll
                for (int w = 0; w < 8; ++w) {
                    unsigned m = qmB[w];
                    while (m) {
                        int t = __ffs(m) - 1; m &= m - 1;
                        int g = w * 32 + t;
                        const float4 gb = gbox[g];
                        float lx = fmaxf(gb.x, pB.x), ly = fmaxf(gb.y, pB.y);
                        float rx = fminf(gb.z, pB.z), ry = fminf(gb.w, pB.w);
                        float ww = fmaxf(rx - lx, 0.0f), hh = fmaxf(ry - ly, 0.0f);
                        float inter = ww * hh;
                        float ga = (gb.z - gb.x) * (gb.w - gb.y);
                        float u  = (ga + apB) - inter;
                        if (inter * ub > ib * u) { ib = inter; ub = u; gstar = g; }
                    }
                }
            }
            posinfo[(size_t)b * NM + jB] =
                ((unsigned)gstar << 16) | (unsigned)gt_labels[b * NG + gstar];
        } else {
            posinfo[(size_t)b * NM + jB] = 0;
        }
    }
}

// ---------------------------------------------------------------------------
// K2: fused per-image sampler + loss (R14-proven, ~4 µs). grid = NB x 256.
// ---------------------------------------------------------------------------
__global__ __launch_bounds__(256) void k2_kernel(
    const float4* __restrict__ props4,
    const float4* __restrict__ gt4,
    const float*  __restrict__ gt_thetas,
    const unsigned int* __restrict__ posinfo,
    const float*  __restrict__ logits,      // [N, 91]
    const float*  __restrict__ boxreg,      // [N, 455]
    const float*  __restrict__ stats,       // [N]
    float2* __restrict__ partials)          // [NB]
{
    __shared__ int sampled[NS];
    __shared__ int wsum[4];

    const int b    = blockIdx.x;
    const int tid  = threadIdx.x;
    const int lane = tid & 63;
    const int wid  = tid >> 6;
    const unsigned* P = posinfo + (size_t)b * NM;
    const int base = tid * 64;

    unsigned long long pm = 0ull;
    int cn = 0;
    if (tid < NSTRIP) {
        const uint4* Pv = reinterpret_cast<const uint4*>(P + base);
        #pragma unroll
        for (int q = 0; q < 16; ++q) {
            uint4 v = Pv[q];
            int e = q * 4;
            if (v.x) pm |= 1ull << (e + 0);
            if (v.y) pm |= 1ull << (e + 1);
            if (v.z) pm |= 1ull << (e + 2);
            if (v.w) pm |= 1ull << (e + 3);
        }
        cn = 64 - __popcll(pm);
    }
    int cp = (tid < NSTRIP) ? __popcll(pm) : 0;
    int val  = (cp << 16) | cn;
    int incl = val;
    #pragma unroll
    for (int off = 1; off < 64; off <<= 1) {
        int u = __shfl_up(incl, off, 64);
        if (lane >= off) incl += u;
    }
    if (lane == 63) wsum[wid] = incl;
    __syncthreads();
    int wbase = 0;
    #pragma unroll
    for (int w = 0; w < 4; ++w) if (w < wid) wbase += wsum[w];
    int tot  = wsum[0] + wsum[1] + wsum[2] + wsum[3];
    int excl = wbase + incl - val;
    int rp = excl >> 16, rn = excl & 0xffff;
    int posT = tot >> 16, negT = tot & 0xffff;
    int np = posT < 128 ? posT : 128;          // n_pos = min(pos_total, S/4)
    int nn = NS - np; if (nn > negT) nn = negT;

    if (tid < NSTRIP) {
        #pragma unroll 4
        for (int e = 0; e < 64; ++e) {
            int idx = base + e;
            if ((pm >> e) & 1ull) {
                if (rp < np) sampled[rp + (rn < nn ? rn : nn)] = idx;
                rp++;
            } else {
                if (rn < nn) sampled[rn + (rp < np ? rp : np)] = idx;
                rn++;
            }
        }
    }
    __syncthreads();
    // Fallback fill (unreachable with this data): unselected ascending.
    if (tid == 0 && np + nn < NS) {
        int cpp = 0, cnn = 0, i = np + nn;
        for (int idx = 0; idx < NM && i < NS; ++idx) {
            bool p = P[idx] != 0;
            bool sel;
            if (p) { sel = cpp < np; cpp++; } else { sel = cnn < nn; cnn++; }
            if (!sel) sampled[i++] = idx;
        }
    }
    __syncthreads();

    // ---- loss phase (2 rows per thread, all in registers) ----
    float cls_acc = 0.0f, box_acc = 0.0f;
    #pragma unroll
    for (int it = 0; it < 2; ++it) {
        const int i = tid + it * 256;
        const int r = b * NS + i;
        const int idx = sampled[i];
        const unsigned info = P[idx];
        int lbl = 0;
        if (info) lbl = info & 0xffff;
        cls_acc += stats[r] - logits[(size_t)r * NCLS + lbl];
        if (info) {
            const int m = info >> 16;
            float4 pv = (idx < NP) ? props4[(size_t)b * NP + idx]
                                   : gt4[(size_t)b * NG + (idx - NP)];
            float4 rv = gt4[(size_t)b * NG + m];
            float pw = pv.z - pv.x, ph = pv.w - pv.y;
            float px = pv.x + 0.5f * pw, py = pv.y + 0.5f * ph;
            float gw = rv.z - rv.x, gh = rv.w - rv.y;
            float gx = rv.x + 0.5f * gw, gy = rv.y + 0.5f * gh;
            float tg[5];
            tg[0] = 10.0f * (gx - px) / pw;
            tg[1] = 10.0f * (gy - py) / ph;
            tg[2] = 5.0f * logf(gw / pw);
            tg[3] = 5.0f * logf(gh / ph);
            tg[4] = gt_thetas[b * NG + m];
            const float* pr = boxreg + (size_t)r * (NCLS * 5) + lbl * 5;
            #pragma unroll
            for (int k = 0; k < 5; ++k) {
                float d  = pr[k] - tg[k];
                float ad = fabsf(d);
                box_acc += (ad < SL1_BETA) ? 0.5f * d * d / SL1_BETA
                                           : ad - 0.5f * SL1_BETA;
            }
        }
    }
    #pragma unroll
    for (int o = 32; o; o >>= 1) {
        cls_acc += __shfl_xor(cls_acc, o, 64);
        box_acc += __shfl_xor(box_acc, o, 64);
    }
    __shared__ float cc[4], bb[4];
    if (lane == 0) { cc[wid] = cls_acc; bb[wid] = box_acc; }
    __syncthreads();
    if (tid == 0)
        partials[b] = make_float2(cc[0] + cc[1] + cc[2] + cc[3],
                                  bb[0] + bb[1] + bb[2] + bb[3]);
}

// ---------------------------------------------------------------------------
// K3: reduce NB float2 partials -> 2 outputs. 1 block x 64.
// ---------------------------------------------------------------------------
__global__ void final_kernel(const float2* __restrict__ partials,
                             float* __restrict__ out)
{
    const int tid = threadIdx.x;
    float2 v = (tid < NB) ? partials[tid] : make_float2(0.f, 0.f);
    float c = v.x, bx = v.y;
    #pragma unroll
    for (int o = 32; o; o >>= 1) {
        c  += __shfl_xor(c, o, 64);
        bx += __shfl_xor(bx, o, 64);
    }
    if (tid == 0) {
        const float invN = 1.0f / (float)(NB * NS);
        out[0] = c * invN;
        out[1] = bx * invN;
    }
}

// ---------------------------------------------------------------------------
extern "C" void kernel_launch(void* const* d_in, const int* in_sizes, int n_in,
                              void* d_out, int out_size, void* d_ws, size_t ws_size,
                              hipStream_t stream)
{
    const float* class_logits   = (const float*)d_in[0];  // [NB*NS, 91]
    const float* box_regression = (const float*)d_in[1];  // [NB*NS, 455]
    const float4* props4        = (const float4*)d_in[2]; // [NB, NP]
    const float4* gt4           = (const float4*)d_in[3]; // [NB, NG]
    const float* gt_thetas      = (const float*)d_in[4];  // [NB, NG]
    const int*   gt_labels      = (const int*)d_in[5];    // [NB, NG]
    float* out = (float*)d_out;

    char* ws = (char*)d_ws;
    unsigned int* posinfo = (unsigned int*)ws;             // NB*NM u32
    char* pend = ws + (((size_t)NB * NM * 4 + 255) & ~255ull);
    float* stats = (float*)pend;                           // NB*NS f32
    float2* partials = (float2*)(pend + (((size_t)NB * NS * 4 + 255) & ~255ull));

    hipLaunchKernelGGL(k1_kernel, dim3(MATCHX + STATSX, NB), dim3(256), 0, stream,
                       props4, gt4, gt_labels, class_logits, posinfo, stats);
    hipLaunchKernelGGL(k2_kernel, dim3(NB), dim3(256), 0, stream,
                       props4, gt4, gt_thetas, posinfo, class_logits,
                       box_regression, stats, partials);
    hipLaunchKernelGGL(final_kernel, dim3(1), dim3(64), 0, stream, partials, out);
}

// Round 16
// 66.382 us; speedup vs baseline: 1.0113x; 1.0113x over previous
//
#include <hip/hip_runtime.h>

#define NB 16           // B images
#define NP 16000        // proposals per image
#define NG 256          // gt boxes per image
#define NM (NP + NG)    // proposals + gt = 16256
#define NSTRIP 254      // NM / 64
#define NS 512          // samples per image
#define NCLS 91
#define SL1_BETA (1.0f/9.0f)
#define MATCHX 64       // match blocks per image (256 proposals each)
#define STATSX 4        // stats blocks per image

// ---------------------------------------------------------------------------
// K1 = match + softmax-stats rider.
// match (bx < 64): T=1 thread-per-proposal (max wave count: 4096 match waves
//   ~ 4.25/SIMD with stats -> latency hidden, the R3-proven occupancy regime).
//   Inner loop = R5-proven exact predicate ONLY:
//     iou >= 0.5  <=>  3*inter >= ap+ga  via  fmaf(inter,3,-tt) >= 0
//   1 ds_read_b128 per GT (single broadcast address, conflict-free); area in
//   VALU. Qualifier masks qm[8] in REGISTERS: outer loop unrolled (8 -> static
//   qm index), inner runtime-32 with unroll 4 (~4KB body, I$-resident; no R7
//   spill, no R14 I$ thrash). qcnt==1 -> argmax free; qcnt>1 (rare) -> exact
//   cross-product argmax over set bits (ascending g + strict improve =
//   first-max tie rule). GT self-rows flow through the generic path.
//   Output: (gstar<<16)|label, 0 = negative.
// stats (bx >= 64): per-row logsumexp (proven rider; hides under match).
// grid = (68, NB) x 256. No atomics, no fences.
// ---------------------------------------------------------------------------
__global__ __launch_bounds__(256) void k1_kernel(
    const float4* __restrict__ props4,      // [NB*NP]
    const float4* __restrict__ gt4,         // [NB*NG]
    const int*    __restrict__ gt_labels,   // [NB*NG]
    const float*  __restrict__ logits,      // [NB*NS, NCLS]
    unsigned int* __restrict__ posinfo,     // [NB*NM]
    float*        __restrict__ stats)       // [NB*NS]
{
    const int b    = blockIdx.y;
    const int bx   = blockIdx.x;
    const int tid  = threadIdx.x;
    const int lane = tid & 63;
    const int wid  = tid >> 6;

    if (bx >= MATCHX) {
        // ---- softmax stats: 64 blocks x 4 waves; 32 rows per wave ----
        const int sid = (bx - MATCHX) * NB + b;          // 0..63
        for (int rr = 0; rr < 32; ++rr) {
            const int r = sid * 128 + wid * 32 + rr;
            const float* row = logits + (size_t)r * NCLS;
            float a = (lane < NCLS)      ? row[lane]      : -3.0e38f;
            float c = (lane + 64 < NCLS) ? row[lane + 64] : -3.0e38f;
            float mx = fmaxf(a, c);
            #pragma unroll
            for (int o = 32; o; o >>= 1) mx = fmaxf(mx, __shfl_xor(mx, o, 64));
            float ss = 0.0f;
            if (lane < NCLS)      ss += expf(a - mx);
            if (lane + 64 < NCLS) ss += expf(c - mx);
            #pragma unroll
            for (int o = 32; o; o >>= 1) ss += __shfl_xor(ss, o, 64);
            if (lane == 0) stats[r] = mx + logf(ss);
        }
        return;
    }

    // ---- match ----
    __shared__ float4 gbox[NG];     // 4 KB (boxes only; area in VALU)

    gbox[tid] = gt4[(size_t)b * NG + tid];
    __syncthreads();

    const int j = bx * 256 + tid;
    if (j >= NM) return;                       // wave-uniform (NM % 64 == 0)

    const float4 pb = (j < NP) ? props4[(size_t)b * NP + j] : gbox[j - NP];
    const float ap = (pb.z - pb.x) * (pb.w - pb.y);

    unsigned qm[8];
    int qcnt = 0, gf = 0;
    #pragma unroll
    for (int w = 0; w < 8; ++w) {              // outer unrolled: qm regs static
        unsigned m = 0;
        #pragma unroll 4
        for (int t = 0; t < 32; ++t) {         // runtime inner: I$-resident
            const float4 gb = gbox[w * 32 + t];              // 1 ds_read_b128
            const float  ga = (gb.z - gb.x) * (gb.w - gb.y); // area in VALU
            float lx = fmaxf(gb.x, pb.x), ly = fmaxf(gb.y, pb.y);
            float rx = fminf(gb.z, pb.z), ry = fminf(gb.w, pb.w);
            float ww = fmaxf(rx - lx, 0.0f), hh = fmaxf(ry - ly, 0.0f);
            float inter = ww * hh;
            float tt = ga + ap;
            if (fmaf(inter, 3.0f, -tt) >= 0.0f) m |= (1u << t);
        }
        qm[w] = m;
        if (qcnt == 0 && m) gf = w * 32 + (__ffs(m) - 1);
        qcnt += __popc(m);
    }

    unsigned info = 0;
    if (qcnt > 0) {
        int gstar = gf;
        if (qcnt > 1) {                        // rare: exact argmax over set bits
            float ib = -1.0f, ub = 1.0f; gstar = 0;
            #pragma unroll
            for (int w = 0; w < 8; ++w) {
                unsigned m = qm[w];
                while (m) {
                    int t = __ffs(m) - 1; m &= m - 1;
                    int g = w * 32 + t;
                    const float4 gb = gbox[g];
                    float lx = fmaxf(gb.x, pb.x), ly = fmaxf(gb.y, pb.y);
                    float rx = fminf(gb.z, pb.z), ry = fminf(gb.w, pb.w);
                    float ww = fmaxf(rx - lx, 0.0f), hh = fmaxf(ry - ly, 0.0f);
                    float inter = ww * hh;
                    float ga = (gb.z - gb.x) * (gb.w - gb.y);
                    float u  = (ga + ap) - inter;
                    // inter/u > ib/ub <=> inter*ub > ib*u ; ascending g +
                    // strict improve == first-max tie rule
                    if (inter * ub > ib * u) { ib = inter; ub = u; gstar = g; }
                }
            }
        }
        info = ((unsigned)gstar << 16) | (unsigned)gt_labels[b * NG + gstar];
    }
    posinfo[(size_t)b * NM + j] = info;        // coalesced, 0 = negative
}

// ---------------------------------------------------------------------------
// K2: fused per-image sampler + loss (R14-proven, ~4 µs). grid = NB x 256.
// ---------------------------------------------------------------------------
__global__ __launch_bounds__(256) void k2_kernel(
    const float4* __restrict__ props4,
    const float4* __restrict__ gt4,
    const float*  __restrict__ gt_thetas,
    const unsigned int* __restrict__ posinfo,
    const float*  __restrict__ logits,      // [N, 91]
    const float*  __restrict__ boxreg,      // [N, 455]
    const float*  __restrict__ stats,       // [N]
    float2* __restrict__ partials)          // [NB]
{
    __shared__ int sampled[NS];
    __shared__ int wsum[4];

    const int b    = blockIdx.x;
    const int tid  = threadIdx.x;
    const int lane = tid & 63;
    const int wid  = tid >> 6;
    const unsigned* P = posinfo + (size_t)b * NM;
    const int base = tid * 64;

    unsigned long long pm = 0ull;
    int cn = 0;
    if (tid < NSTRIP) {
        const uint4* Pv = reinterpret_cast<const uint4*>(P + base);
        #pragma unroll
        for (int q = 0; q < 16; ++q) {
            uint4 v = Pv[q];
            int e = q * 4;
            if (v.x) pm |= 1ull << (e + 0);
            if (v.y) pm |= 1ull << (e + 1);
            if (v.z) pm |= 1ull << (e + 2);
            if (v.w) pm |= 1ull << (e + 3);
        }
        cn = 64 - __popcll(pm);
    }
    int cp = (tid < NSTRIP) ? __popcll(pm) : 0;
    int val  = (cp << 16) | cn;
    int incl = val;
    #pragma unroll
    for (int off = 1; off < 64; off <<= 1) {
        int u = __shfl_up(incl, off, 64);
        if (lane >= off) incl += u;
    }
    if (lane == 63) wsum[wid] = incl;
    __syncthreads();
    int wbase = 0;
    #pragma unroll
    for (int w = 0; w < 4; ++w) if (w < wid) wbase += wsum[w];
    int tot  = wsum[0] + wsum[1] + wsum[2] + wsum[3];
    int excl = wbase + incl - val;
    int rp = excl >> 16, rn = excl & 0xffff;
    int posT = tot >> 16, negT = tot & 0xffff;
    int np = posT < 128 ? posT : 128;          // n_pos = min(pos_total, S/4)
    int nn = NS - np; if (nn > negT) nn = negT;

    if (tid < NSTRIP) {
        #pragma unroll 4
        for (int e = 0; e < 64; ++e) {
            int idx = base + e;
            if ((pm >> e) & 1ull) {
                if (rp < np) sampled[rp + (rn < nn ? rn : nn)] = idx;
                rp++;
            } else {
                if (rn < nn) sampled[rn + (rp < np ? rp : np)] = idx;
                rn++;
            }
        }
    }
    __syncthreads();
    // Fallback fill (unreachable with this data): unselected ascending.
    if (tid == 0 && np + nn < NS) {
        int cpp = 0, cnn = 0, i = np + nn;
        for (int idx = 0; idx < NM && i < NS; ++idx) {
            bool p = P[idx] != 0;
            bool sel;
            if (p) { sel = cpp < np; cpp++; } else { sel = cnn < nn; cnn++; }
            if (!sel) sampled[i++] = idx;
        }
    }
    __syncthreads();

    // ---- loss phase (2 rows per thread, all in registers) ----
    float cls_acc = 0.0f, box_acc = 0.0f;
    #pragma unroll
    for (int it = 0; it < 2; ++it) {
        const int i = tid + it * 256;
        const int r = b * NS + i;
        const int idx = sampled[i];
        const unsigned info = P[idx];
        int lbl = 0;
        if (info) lbl = info & 0xffff;
        cls_acc += stats[r] - logits[(size_t)r * NCLS + lbl];
        if (info) {
            const int m = info >> 16;
            float4 pv = (idx < NP) ? props4[(size_t)b * NP + idx]
                                   : gt4[(size_t)b * NG + (idx - NP)];
            float4 rv = gt4[(size_t)b * NG + m];
            float pw = pv.z - pv.x, ph = pv.w - pv.y;
            float px = pv.x + 0.5f * pw, py = pv.y + 0.5f * ph;
            float gw = rv.z - rv.x, gh = rv.w - rv.y;
            float gx = rv.x + 0.5f * gw, gy = rv.y + 0.5f * gh;
            float tg[5];
            tg[0] = 10.0f * (gx - px) / pw;
            tg[1] = 10.0f * (gy - py) / ph;
            tg[2] = 5.0f * logf(gw / pw);
            tg[3] = 5.0f * logf(gh / ph);
            tg[4] = gt_thetas[b * NG + m];
            const float* pr = boxreg + (size_t)r * (NCLS * 5) + lbl * 5;
            #pragma unroll
            for (int k = 0; k < 5; ++k) {
                float d  = pr[k] - tg[k];
                float ad = fabsf(d);
                box_acc += (ad < SL1_BETA) ? 0.5f * d * d / SL1_BETA
                                           : ad - 0.5f * SL1_BETA;
            }
        }
    }
    #pragma unroll
    for (int o = 32; o; o >>= 1) {
        cls_acc += __shfl_xor(cls_acc, o, 64);
        box_acc += __shfl_xor(box_acc, o, 64);
    }
    __shared__ float cc[4], bb[4];
    if (lane == 0) { cc[wid] = cls_acc; bb[wid] = box_acc; }
    __syncthreads();
    if (tid == 0)
        partials[b] = make_float2(cc[0] + cc[1] + cc[2] + cc[3],
                                  bb[0] + bb[1] + bb[2] + bb[3]);
}

// ---------------------------------------------------------------------------
// K3: reduce NB float2 partials -> 2 outputs. 1 block x 64.
// ---------------------------------------------------------------------------
__global__ void final_kernel(const float2* __restrict__ partials,
                             float* __restrict__ out)
{
    const int tid = threadIdx.x;
    float2 v = (tid < NB) ? partials[tid] : make_float2(0.f, 0.f);
    float c = v.x, bx = v.y;
    #pragma unroll
    for (int o = 32; o; o >>= 1) {
        c  += __shfl_xor(c, o, 64);
        bx += __shfl_xor(bx, o, 64);
    }
    if (tid == 0) {
        const float invN = 1.0f / (float)(NB * NS);
        out[0] = c * invN;
        out[1] = bx * invN;
    }
}

// ---------------------------------------------------------------------------
extern "C" void kernel_launch(void* const* d_in, const int* in_sizes, int n_in,
                              void* d_out, int out_size, void* d_ws, size_t ws_size,
                              hipStream_t stream)
{
    const float* class_logits   = (const float*)d_in[0];  // [NB*NS, 91]
    const float* box_regression = (const float*)d_in[1];  // [NB*NS, 455]
    const float4* props4        = (const float4*)d_in[2]; // [NB, NP]
    const float4* gt4           = (const float4*)d_in[3]; // [NB, NG]
    const float* gt_thetas      = (const float*)d_in[4];  // [NB, NG]
    const int*   gt_labels      = (const int*)d_in[5];    // [NB, NG]
    float* out = (float*)d_out;

    char* ws = (char*)d_ws;
    unsigned int* posinfo = (unsigned int*)ws;             // NB*NM u32
    char* pend = ws + (((size_t)NB * NM * 4 + 255) & ~255ull);
    float* stats = (float*)pend;                           // NB*NS f32
    float2* partials = (float2*)(pend + (((size_t)NB * NS * 4 + 255) & ~255ull));

    hipLaunchKernelGGL(k1_kernel, dim3(MATCHX + STATSX, NB), dim3(256), 0, stream,
                       props4, gt4, gt_labels, class_logits, posinfo, stats);
    hipLaunchKernelGGL(k2_kernel, dim3(NB), dim3(256), 0, stream,
                       props4, gt4, gt_thetas, posinfo, class_logits,
                       box_regression, stats, partials);
    hipLaunchKernelGGL(final_kernel, dim3(1), dim3(64), 0, stream, partials, out);
}